// Round 3
// baseline (845.160 us; speedup 1.0000x reference)
//
#include <hip/hip_runtime.h>
#include <stdint.h>

typedef int v4i __attribute__((ext_vector_type(4)));
typedef unsigned long long ull;

#define GLOAD16(g, l)                                                          \
  __builtin_amdgcn_global_load_lds(                                            \
      (const __attribute__((address_space(1))) void*)(g),                      \
      (__attribute__((address_space(3))) void*)(l), 16, 0, 0)

__device__ __forceinline__ signed char sgnf(float v) {
  return v > 0.f ? (signed char)1 : (v < 0.f ? (signed char)-1 : (signed char)0);
}

// ---------------- binarize fp32 -> i8 sign ----------------
__global__ void k_bin(const float4* __restrict__ in, char4* __restrict__ out, int n4) {
  int i = blockIdx.x * blockDim.x + threadIdx.x;
  int stride = gridDim.x * blockDim.x;
  for (; i < n4; i += stride) {
    float4 v = in[i];
    char4 o;
    o.x = sgnf(v.x); o.y = sgnf(v.y); o.z = sgnf(v.z); o.w = sgnf(v.w);
    out[i] = o;
  }
}

// ---------------- i8 binary GEMM: A[M,N] = X[M,K] * W[N,K]^T, + fused col stats ----
// T3 minimum-2-phase: double-buffered LDS, STAGE(next) issued BEFORE compute(cur),
// single __syncthreads() per K-step (vmcnt drain lands after MFMAs -> loads hidden).
// global_load_lds: linear LDS dest + inverse-swizzled global source + swizzled read.
#define BM 128
#define BN 128
#define BKB 128

__global__ __launch_bounds__(256, 2) void k_bgemm(
    const signed char* __restrict__ X, const signed char* __restrict__ W,
    short* __restrict__ A, ull* __restrict__ S, int M, int N, int K)
{
  __shared__ __align__(16) signed char As[2][BM * BKB];
  __shared__ __align__(16) signed char Bs[2][BN * BKB];
  const int t = threadIdx.x;
  const int lane = t & 63;
  const int wave = t >> 6;
  const int wm = wave >> 1, wn = wave & 1;
  const int bm = blockIdx.y * BM, bn = blockIdx.x * BN;

  // per-lane source-swizzle geometry for staging (8 rows x 128B per wave-issue)
  const int srow = lane >> 3;            // 0..7 row within chunk
  const int sslot = (lane & 7);          // linear 16B slot within row

  const signed char* Xb0 = X + (size_t)bm * K;
  const signed char* Wb0 = W + (size_t)bn * K;

  v4i acc[4][4] = {};
  const int nt = K / BKB;

#define STAGE(buf, k0)                                                         \
  {                                                                            \
    _Pragma("unroll")                                                          \
    for (int c = 0; c < 4; ++c) {                                              \
      int br = (wave * 4 + c) * 8;                                             \
      int row = br + srow;                                                     \
      int ss = sslot ^ (row & 7);                                              \
      GLOAD16(Xb0 + (size_t)row * K + (k0) + ss * 16, As[buf] + br * BKB);     \
      GLOAD16(Wb0 + (size_t)row * K + (k0) + ss * 16, Bs[buf] + br * BKB);     \
    }                                                                          \
  }

  STAGE(0, 0);
  __syncthreads();          // drain prologue loads

  int cur = 0;
  for (int tile = 0; tile < nt; ++tile) {
    if (tile + 1 < nt) STAGE(cur ^ 1, (tile + 1) * BKB);   // prefetch in flight
#pragma unroll
    for (int kk = 0; kk < 2; ++kk) {
      v4i af[4], bf[4];
#pragma unroll
      for (int m = 0; m < 4; ++m) {
        int row = wm * 64 + m * 16 + (lane & 15);
        int slot = ((kk << 2) | (lane >> 4)) ^ (row & 7);   // swizzle on READ
        af[m] = *(const v4i*)(As[cur] + row * BKB + slot * 16);
      }
#pragma unroll
      for (int n = 0; n < 4; ++n) {
        int row = wn * 64 + n * 16 + (lane & 15);
        int slot = ((kk << 2) | (lane >> 4)) ^ (row & 7);
        bf[n] = *(const v4i*)(Bs[cur] + row * BKB + slot * 16);
      }
#pragma unroll
      for (int m = 0; m < 4; ++m)
#pragma unroll
        for (int n = 0; n < 4; ++n)
          acc[m][n] = __builtin_amdgcn_mfma_i32_16x16x64_i8(af[m], bf[n], acc[m][n], 0, 0, 0);
    }
    __syncthreads();        // drains vmcnt (prefetch landed) + lgkm; buffers swap
    cur ^= 1;
  }
#undef STAGE

  // C layout (verified): col = lane&15, row = (lane>>4)*4 + reg
#pragma unroll
  for (int m = 0; m < 4; ++m) {
    int rbase = bm + wm * 64 + m * 16 + (lane >> 4) * 4;
#pragma unroll
    for (int n = 0; n < 4; ++n) {
      int col = bn + wn * 64 + n * 16 + (lane & 15);
#pragma unroll
      for (int r = 0; r < 4; ++r)
        A[(size_t)(rbase + r) * N + col] = (short)acc[m][n][r];
    }
  }

  // fused per-column stats: sum and sumsq of this block's 128 rows (int exact,
  // deterministic: integer atomics are associative)
#pragma unroll
  for (int n = 0; n < 4; ++n) {
    int s = 0, q = 0;
#pragma unroll
    for (int m = 0; m < 4; ++m)
#pragma unroll
      for (int r = 0; r < 4; ++r) {
        int v = acc[m][n][r];
        s += v; q += v * v;
      }
    s += __shfl_xor(s, 16); s += __shfl_xor(s, 32);
    q += __shfl_xor(q, 16); q += __shfl_xor(q, 32);
    if ((lane >> 4) == 0) {
      int col = bn + wn * 64 + n * 16 + (lane & 15);
      atomicAdd(&S[col], (ull)(long long)s);
      atomicAdd(&S[(size_t)N + col], (ull)(long long)q);
    }
  }
}

// ---------------- stats -> (mean, g*rsqrt(var+eps)) per column ----------------
__global__ void k_finalize(const ull* __restrict__ sums, const float* __restrict__ g,
                           int M, int N, float* __restrict__ meanf, float* __restrict__ sgf) {
  int j = blockIdx.x * blockDim.x + threadIdx.x;
  if (j >= N) return;
  double sum = (double)(long long)sums[j];
  double sumsq = (double)(long long)sums[N + j];
  double mean = sum / (double)M;
  double var = sumsq / (double)M - mean * mean;
  if (var < 0.0) var = 0.0;
  double inv = 1.0 / sqrt(var + 1e-5);
  meanf[j] = (float)mean;
  sgf[j] = (float)(inv * (double)g[j]);
}

// ---------------- sign(batchnorm(a)) -> i8 (bias cancels under BN) ----------------
__global__ void k_signbn(const short4* __restrict__ A4, const float* __restrict__ meanf,
                         const float* __restrict__ sgf, const float* __restrict__ be,
                         char4* __restrict__ X4, int total4, int nmask) {
  int i = blockIdx.x * blockDim.x + threadIdx.x;
  int stride = gridDim.x * blockDim.x;
  for (; i < total4; i += stride) {
    short4 a = A4[i];
    int c0 = (i * 4) & nmask;
    char4 o;
    o.x = sgnf(((float)a.x - meanf[c0    ]) * sgf[c0    ] + be[c0    ]);
    o.y = sgnf(((float)a.y - meanf[c0 + 1]) * sgf[c0 + 1] + be[c0 + 1]);
    o.z = sgnf(((float)a.z - meanf[c0 + 2]) * sgf[c0 + 2] + be[c0 + 2]);
    o.w = sgnf(((float)a.w - meanf[c0 + 3]) * sgf[c0 + 3] + be[c0 + 3]);
    X4[i] = o;
  }
}

// ---------------- fused layers 3,4,5: X3[M,256] -> A5[M,10] + stats ----------------
__global__ __launch_bounds__(256) void k_tail(
    const signed char* __restrict__ X3, const signed char* __restrict__ W3,
    const signed char* __restrict__ W4, const signed char* __restrict__ W5,
    const float* __restrict__ b3, const float* __restrict__ b4,
    int* __restrict__ A5, ull* __restrict__ sums5, int M)
{
  __shared__ __align__(16) signed char sW3[16 * 256];
  __shared__ __align__(16) signed char sW4[256];
  __shared__ __align__(16) signed char sW5[160];
  __shared__ __align__(16) signed char sX[16 * 256];
  __shared__ signed char sH[16][16];
  __shared__ int bsum[10], bsq[10];
  int t = threadIdx.x;
  int rowBlock = blockIdx.x * 16;
  ((int4*)sW3)[t] = ((const int4*)W3)[t];
  ((int4*)sX)[t] = ((const int4*)(X3 + (size_t)rowBlock * 256))[t];
  if (t < 16) ((int4*)sW4)[t] = ((const int4*)W4)[t];
  if (t < 10) {
    ((int4*)sW5)[t] = ((const int4*)W5)[t];
    bsum[t] = 0; bsq[t] = 0;
  }
  __syncthreads();
  int r = t >> 4, j = t & 15;
  int d3 = 0;
#pragma unroll 8
  for (int k = 0; k < 256; ++k) d3 += (int)sX[r * 256 + k] * (int)sW3[j * 256 + k];
  sH[r][j] = sgnf((float)d3 + b3[j]);   // sign(hardtanh(z)) == sign(z)
  __syncthreads();
  int d4 = 0;
#pragma unroll
  for (int k = 0; k < 16; ++k) d4 += (int)sH[r][k] * (int)sW4[j * 16 + k];
  signed char x5 = sgnf((float)d4 + b4[j]);
  __syncthreads();
  sH[r][j] = x5;
  __syncthreads();
  if (j < 10) {
    int d5 = 0;
#pragma unroll
    for (int k = 0; k < 16; ++k) d5 += (int)sH[r][k] * (int)sW5[j * 16 + k];
    A5[(size_t)(rowBlock + r) * 10 + j] = d5;
    atomicAdd(&bsum[j], d5);
    atomicAdd(&bsq[j], d5 * d5);
  }
  __syncthreads();
  if (t < 10) {
    atomicAdd(&sums5[t], (ull)(long long)bsum[t]);
    atomicAdd(&sums5[10 + t], (ull)(long long)bsq[t]);
  }
}

// ---------------- final BN + log_softmax ----------------
__global__ void k_lsm(const int* __restrict__ A5, const float* __restrict__ meanf,
                      const float* __restrict__ sgf, const float* __restrict__ be,
                      float* __restrict__ out, int M) {
  int r = blockIdx.x * blockDim.x + threadIdx.x;
  if (r >= M) return;
  float tv[10]; float mx = -3.0e38f;
#pragma unroll
  for (int j = 0; j < 10; ++j) {
    tv[j] = ((float)A5[(size_t)r * 10 + j] - meanf[j]) * sgf[j] + be[j];
    mx = fmaxf(mx, tv[j]);
  }
  float s = 0.f;
#pragma unroll
  for (int j = 0; j < 10; ++j) s += expf(tv[j] - mx);
  float lse = mx + logf(s);
#pragma unroll
  for (int j = 0; j < 10; ++j) out[(size_t)r * 10 + j] = tv[j] - lse;
}

extern "C" void kernel_launch(void* const* d_in, const int* in_sizes, int n_in,
                              void* d_out, int out_size, void* d_ws, size_t ws_size,
                              hipStream_t stream) {
  const float* x   = (const float*)d_in[0];
  const float* w0f = (const float*)d_in[1];
  const float* w1f = (const float*)d_in[3];
  const float* w2f = (const float*)d_in[5];
  const float* w3f = (const float*)d_in[7];  const float* b3f = (const float*)d_in[8];
  const float* w4f = (const float*)d_in[9];  const float* b4f = (const float*)d_in[10];
  const float* w5f = (const float*)d_in[11];
  const float* g0 = (const float*)d_in[13]; const float* be0 = (const float*)d_in[14];
  const float* g1 = (const float*)d_in[15]; const float* be1 = (const float*)d_in[16];
  const float* g2 = (const float*)d_in[17]; const float* be2 = (const float*)d_in[18];
  const float* g3 = (const float*)d_in[19]; const float* be3 = (const float*)d_in[20];

  const int M = in_sizes[0] / 3072;   // 16384
  char* w = (char*)d_ws;
  short* Abuf      = (short*)w;                          // 134217728
  signed char* X0  = (signed char*)(w + 134217728);      // 50331648
  signed char* Xb  = (signed char*)(w + 184549376);      // 67108864
  signed char* X3  = (signed char*)(w + 251658240);      // 4194304
  signed char* Ws0 = (signed char*)(w + 255852544);      // 12582912
  signed char* Ws1 = (signed char*)(w + 268435456);      // 16777216
  signed char* Ws2 = (signed char*)(w + 285212672);      // 1048576
  signed char* Ws3 = (signed char*)(w + 286261248);      // 4096
  signed char* Ws4 = (signed char*)(w + 286265344);      // 256
  signed char* Ws5 = (signed char*)(w + 286265600);      // 256 (160 used)
  int* A5          = (int*)(w + 286265856);              // 655360
  ull* S0          = (ull*)(w + 286921216);              // 65536
  ull* S1          = (ull*)(w + 286986752);              // 65536
  ull* S2          = (ull*)(w + 287052288);              // 4096
  ull* S5          = (ull*)(w + 287056384);              // 256 (160 used)
  float* P0m = (float*)(w + 287056640); float* P0s = (float*)(w + 287073024);
  float* P1m = (float*)(w + 287089408); float* P1s = (float*)(w + 287105792);
  float* P2m = (float*)(w + 287122176); float* P2s = (float*)(w + 287123200);
  float* P5m = (float*)(w + 287124224); float* P5s = (float*)(w + 287124288);

  // zero all stat accumulators (atomics accumulate fresh each call)
  hipMemsetAsync(w + 286921216, 0, 135424, stream);

  auto bin = [&](const float* src, signed char* dst, int n) {
    int n4 = n / 4;
    int grid = (n4 + 255) / 256; if (grid > 8192) grid = 8192;
    k_bin<<<grid, 256, 0, stream>>>((const float4*)src, (char4*)dst, n4);
  };
  bin(x,   X0,  M * 3072);
  bin(w0f, Ws0, 4096 * 3072);
  bin(w1f, Ws1, 4096 * 4096);
  bin(w2f, Ws2, 256 * 4096);
  bin(w3f, Ws3, 16 * 256);
  bin(w4f, Ws4, 16 * 16);
  bin(w5f, Ws5, 10 * 16);

  // Layer 0: [M,3072] x [4096,3072]^T  (stats fused into GEMM epilogue)
  k_bgemm<<<dim3(4096 / BN, M / BM), 256, 0, stream>>>(X0, Ws0, Abuf, S0, M, 4096, 3072);
  k_finalize<<<16, 256, 0, stream>>>(S0, g0, M, 4096, P0m, P0s);
  k_signbn<<<8192, 256, 0, stream>>>((const short4*)Abuf, P0m, P0s, be0, (char4*)Xb, M * 4096 / 4, 4095);

  // Layer 1: [M,4096] x [4096,4096]^T
  k_bgemm<<<dim3(4096 / BN, M / BM), 256, 0, stream>>>(Xb, Ws1, Abuf, S1, M, 4096, 4096);
  k_finalize<<<16, 256, 0, stream>>>(S1, g1, M, 4096, P1m, P1s);
  k_signbn<<<8192, 256, 0, stream>>>((const short4*)Abuf, P1m, P1s, be1, (char4*)Xb, M * 4096 / 4, 4095);

  // Layer 2: [M,4096] x [256,4096]^T
  k_bgemm<<<dim3(256 / BN, M / BM), 256, 0, stream>>>(Xb, Ws2, Abuf, S2, M, 256, 4096);
  k_finalize<<<1, 256, 0, stream>>>(S2, g2, M, 256, P2m, P2s);
  k_signbn<<<4096, 256, 0, stream>>>((const short4*)Abuf, P2m, P2s, be2, (char4*)X3, M * 256 / 4, 255);

  // Layers 3-5 fused + L5 stats
  k_tail<<<M / 16, 256, 0, stream>>>(X3, Ws3, Ws4, Ws5, b3f, b4f, A5, S5, M);
  k_finalize<<<1, 32, 0, stream>>>(S5, g3, M, 10, P5m, P5s);
  k_lsm<<<(M + 255) / 256, 256, 0, stream>>>(A5, P5m, P5s, be3, (float*)d_out, M);

  (void)n_in; (void)out_size; (void)ws_size;
}

// Round 4
// 471.222 us; speedup vs baseline: 1.7936x; 1.7936x over previous
//
#include <hip/hip_runtime.h>
#include <stdint.h>

typedef int v4i __attribute__((ext_vector_type(4)));
typedef int v8i __attribute__((ext_vector_type(8)));
typedef float v4f __attribute__((ext_vector_type(4)));
typedef short v8s __attribute__((ext_vector_type(8)));
typedef unsigned long long ull;
typedef unsigned int uint;

#define GLOAD16(g, l)                                                          \
  __builtin_amdgcn_global_load_lds(                                            \
      (const __attribute__((address_space(1))) void*)(g),                      \
      (__attribute__((address_space(3))) void*)(l), 16, 0, 0)

__device__ __forceinline__ signed char sgnf(float v) {
  return v > 0.f ? (signed char)1 : (v < 0.f ? (signed char)-1 : (signed char)0);
}
// fp4 e2m1 codes: +1.0 = 0x2, -1.0 = 0xA, 0.0 = 0x0
__device__ __forceinline__ uint nib(float v) {
  return v > 0.f ? 2u : (v < 0.f ? 10u : 0u);
}

// ---------------- binarize fp32 -> i8 sign (tiny weights only) ----------------
__global__ void k_bin(const float4* __restrict__ in, char4* __restrict__ out, int n4) {
  int i = blockIdx.x * blockDim.x + threadIdx.x;
  int stride = gridDim.x * blockDim.x;
  for (; i < n4; i += stride) {
    float4 v = in[i];
    char4 o;
    o.x = sgnf(v.x); o.y = sgnf(v.y); o.z = sgnf(v.z); o.w = sgnf(v.w);
    out[i] = o;
  }
}

// ---------------- binarize fp32 -> packed fp4 (2 elems/byte) ----------------
__global__ void k_binp(const float4* __restrict__ in, uint* __restrict__ out, int n8) {
  int i = blockIdx.x * blockDim.x + threadIdx.x;
  int stride = gridDim.x * blockDim.x;
  for (; i < n8; i += stride) {
    float4 a = in[i * 2], b = in[i * 2 + 1];
    out[i] = nib(a.x) | (nib(a.y) << 4) | (nib(a.z) << 8) | (nib(a.w) << 12) |
             (nib(b.x) << 16) | (nib(b.y) << 20) | (nib(b.z) << 24) | (nib(b.w) << 28);
  }
}

// ---------------- MX-fp4 binary GEMM: A[M,N] = X[M,K] * W[N,K]^T + fused stats ----
// R2-verified 2-barrier m97 structure, single-buffer 32KB LDS. K in ELEMENTS;
// packed fp4 rows (K/2 bytes). One 128B LDS row = 256 K-elements -> K-steps halve
// vs i8. All MX scales = 0x7F (x1.0): exact integer arithmetic in f32 accum.
#define BM 128
#define BN 128

__global__ __launch_bounds__(256, 2) void k_bgemm(
    const unsigned char* __restrict__ X, const unsigned char* __restrict__ W,
    short* __restrict__ A, ull* __restrict__ S, int M, int N, int K)
{
  __shared__ __align__(16) unsigned char As[BM * 128];
  __shared__ __align__(16) unsigned char Bs[BN * 128];
  const int Kb = K >> 1;                 // packed row stride in bytes
  const int t = threadIdx.x;
  const int lane = t & 63;
  const int wave = t >> 6;
  const int wm = wave >> 1, wn = wave & 1;
  const int bm = blockIdx.y * BM, bn = blockIdx.x * BN;

  const int srow = lane >> 3;            // 0..7 row within 8-row chunk
  const int sslot = (lane & 7);          // linear 16B slot within row

  const unsigned char* Xb0 = X + (size_t)bm * Kb;
  const unsigned char* Wb0 = W + (size_t)bn * Kb;

  v4f acc[4][4] = {};
  // fp4 operands use the low 4 VGPRs of the 8-reg field; zero the highs once
  // (loop-carried -> no per-iteration movs)
  v8i a8[4], b8[4];
#pragma unroll
  for (int m = 0; m < 4; ++m) { a8[m] = (v8i)(0); b8[m] = (v8i)(0); }

  const int nt = K / 256;                // 256 elements (128 B) per K-step

  for (int tile = 0; tile < nt; ++tile) {
    int kb0 = tile * 128;                // byte offset into packed row
#pragma unroll
    for (int c = 0; c < 4; ++c) {
      int br = (wave * 4 + c) * 8;       // base row of this 8-row chunk
      int row = br + srow;
      int ss = sslot ^ (row & 7);        // inverse swizzle on SOURCE
      GLOAD16(Xb0 + (size_t)row * Kb + kb0 + ss * 16, As + br * 128);
      GLOAD16(Wb0 + (size_t)row * Kb + kb0 + ss * 16, Bs + br * 128);
    }
    __syncthreads();                     // drains vmcnt + barrier
#pragma unroll
    for (int kk = 0; kk < 2; ++kk) {     // kk = 64-byte (128-element) half
#pragma unroll
      for (int m = 0; m < 4; ++m) {
        int row = wm * 64 + m * 16 + (lane & 15);
        int slot = ((kk << 2) | (lane >> 4)) ^ (row & 7);   // swizzle on READ
        v4i tmp = *(const v4i*)(As + row * 128 + slot * 16);
        a8[m][0] = tmp[0]; a8[m][1] = tmp[1]; a8[m][2] = tmp[2]; a8[m][3] = tmp[3];
      }
#pragma unroll
      for (int n = 0; n < 4; ++n) {
        int row = wn * 64 + n * 16 + (lane & 15);
        int slot = ((kk << 2) | (lane >> 4)) ^ (row & 7);
        v4i tmp = *(const v4i*)(Bs + row * 128 + slot * 16);
        b8[n][0] = tmp[0]; b8[n][1] = tmp[1]; b8[n][2] = tmp[2]; b8[n][3] = tmp[3];
      }
#pragma unroll
      for (int m = 0; m < 4; ++m)
#pragma unroll
        for (int n = 0; n < 4; ++n)
          acc[m][n] = __builtin_amdgcn_mfma_scale_f32_16x16x128_f8f6f4(
              a8[m], b8[n], acc[m][n], 4 /*fp4*/, 4 /*fp4*/,
              0, 0x7F7F7F7Fu, 0, 0x7F7F7F7Fu);
    }
    __syncthreads();                     // compute done before next overwrite
  }

  // C layout (shape-determined, verified): col = lane&15, row = (lane>>4)*4 + reg
#pragma unroll
  for (int m = 0; m < 4; ++m) {
    int rbase = bm + wm * 64 + m * 16 + (lane >> 4) * 4;
#pragma unroll
    for (int n = 0; n < 4; ++n) {
      int col = bn + wn * 64 + n * 16 + (lane & 15);
#pragma unroll
      for (int r = 0; r < 4; ++r)
        A[(size_t)(rbase + r) * N + col] = (short)(int)acc[m][n][r];
    }
  }

  // fused per-column stats (exact ints; deterministic integer atomics)
#pragma unroll
  for (int n = 0; n < 4; ++n) {
    int s = 0, q = 0;
#pragma unroll
    for (int m = 0; m < 4; ++m)
#pragma unroll
      for (int r = 0; r < 4; ++r) {
        int v = (int)acc[m][n][r];
        s += v; q += v * v;
      }
    s += __shfl_xor(s, 16); s += __shfl_xor(s, 32);
    q += __shfl_xor(q, 16); q += __shfl_xor(q, 32);
    if ((lane >> 4) == 0) {
      int col = bn + wn * 64 + n * 16 + (lane & 15);
      atomicAdd(&S[col], (ull)(long long)s);
      atomicAdd(&S[(size_t)N + col], (ull)(long long)q);
    }
  }
}

// ---------------- stats -> (mean, g*rsqrt(var+eps)) per column ----------------
__global__ void k_finalize(const ull* __restrict__ sums, const float* __restrict__ g,
                           int M, int N, float* __restrict__ meanf, float* __restrict__ sgf) {
  int j = blockIdx.x * blockDim.x + threadIdx.x;
  if (j >= N) return;
  double sum = (double)(long long)sums[j];
  double sumsq = (double)(long long)sums[N + j];
  double mean = sum / (double)M;
  double var = sumsq / (double)M - mean * mean;
  if (var < 0.0) var = 0.0;
  double inv = 1.0 / sqrt(var + 1e-5);
  meanf[j] = (float)mean;
  sgf[j] = (float)(inv * (double)g[j]);
}

// ---------------- sign(batchnorm(a)) -> packed fp4 (bias cancels under BN) ----
__global__ void k_signbn_pack(const short* __restrict__ A, const float* __restrict__ meanf,
                              const float* __restrict__ sgf, const float* __restrict__ be,
                              uint* __restrict__ Xp, int total8, int nmask) {
  int i = blockIdx.x * blockDim.x + threadIdx.x;
  int stride = gridDim.x * blockDim.x;
  for (; i < total8; i += stride) {
    v8s a = *(const v8s*)(A + (size_t)i * 8);
    int c0 = (i * 8) & nmask;
    uint b = 0;
#pragma unroll
    for (int j = 0; j < 8; ++j) {
      float z = ((float)a[j] - meanf[c0 + j]) * sgf[c0 + j] + be[c0 + j];
      b |= nib(z) << (4 * j);
    }
    Xp[i] = b;
  }
}

// ---------------- sign(batchnorm(a)) -> i8 (for the tail) ----------------
__global__ void k_signbn(const short4* __restrict__ A4, const float* __restrict__ meanf,
                         const float* __restrict__ sgf, const float* __restrict__ be,
                         char4* __restrict__ X4, int total4, int nmask) {
  int i = blockIdx.x * blockDim.x + threadIdx.x;
  int stride = gridDim.x * blockDim.x;
  for (; i < total4; i += stride) {
    short4 a = A4[i];
    int c0 = (i * 4) & nmask;
    char4 o;
    o.x = sgnf(((float)a.x - meanf[c0    ]) * sgf[c0    ] + be[c0    ]);
    o.y = sgnf(((float)a.y - meanf[c0 + 1]) * sgf[c0 + 1] + be[c0 + 1]);
    o.z = sgnf(((float)a.z - meanf[c0 + 2]) * sgf[c0 + 2] + be[c0 + 2]);
    o.w = sgnf(((float)a.w - meanf[c0 + 3]) * sgf[c0 + 3] + be[c0 + 3]);
    X4[i] = o;
  }
}

// ---------------- fused layers 3,4,5: X3[M,256] -> A5[M,10] + stats ----------------
__global__ __launch_bounds__(256) void k_tail(
    const signed char* __restrict__ X3, const signed char* __restrict__ W3,
    const signed char* __restrict__ W4, const signed char* __restrict__ W5,
    const float* __restrict__ b3, const float* __restrict__ b4,
    int* __restrict__ A5, ull* __restrict__ sums5, int M)
{
  __shared__ __align__(16) signed char sW3[16 * 256];
  __shared__ __align__(16) signed char sW4[256];
  __shared__ __align__(16) signed char sW5[160];
  __shared__ __align__(16) signed char sX[16 * 256];
  __shared__ signed char sH[16][16];
  __shared__ int bsum[10], bsq[10];
  int t = threadIdx.x;
  int rowBlock = blockIdx.x * 16;
  ((int4*)sW3)[t] = ((const int4*)W3)[t];
  ((int4*)sX)[t] = ((const int4*)(X3 + (size_t)rowBlock * 256))[t];
  if (t < 16) ((int4*)sW4)[t] = ((const int4*)W4)[t];
  if (t < 10) {
    ((int4*)sW5)[t] = ((const int4*)W5)[t];
    bsum[t] = 0; bsq[t] = 0;
  }
  __syncthreads();
  int r = t >> 4, j = t & 15;
  int d3 = 0;
#pragma unroll 8
  for (int k = 0; k < 256; ++k) d3 += (int)sX[r * 256 + k] * (int)sW3[j * 256 + k];
  sH[r][j] = sgnf((float)d3 + b3[j]);   // sign(hardtanh(z)) == sign(z)
  __syncthreads();
  int d4 = 0;
#pragma unroll
  for (int k = 0; k < 16; ++k) d4 += (int)sH[r][k] * (int)sW4[j * 16 + k];
  signed char x5 = sgnf((float)d4 + b4[j]);
  __syncthreads();
  sH[r][j] = x5;
  __syncthreads();
  if (j < 10) {
    int d5 = 0;
#pragma unroll
    for (int k = 0; k < 16; ++k) d5 += (int)sH[r][k] * (int)sW5[j * 16 + k];
    A5[(size_t)(rowBlock + r) * 10 + j] = d5;
    atomicAdd(&bsum[j], d5);
    atomicAdd(&bsq[j], d5 * d5);
  }
  __syncthreads();
  if (t < 10) {
    atomicAdd(&sums5[t], (ull)(long long)bsum[t]);
    atomicAdd(&sums5[10 + t], (ull)(long long)bsq[t]);
  }
}

// ---------------- final BN + log_softmax ----------------
__global__ void k_lsm(const int* __restrict__ A5, const float* __restrict__ meanf,
                      const float* __restrict__ sgf, const float* __restrict__ be,
                      float* __restrict__ out, int M) {
  int r = blockIdx.x * blockDim.x + threadIdx.x;
  if (r >= M) return;
  float tv[10]; float mx = -3.0e38f;
#pragma unroll
  for (int j = 0; j < 10; ++j) {
    tv[j] = ((float)A5[(size_t)r * 10 + j] - meanf[j]) * sgf[j] + be[j];
    mx = fmaxf(mx, tv[j]);
  }
  float s = 0.f;
#pragma unroll
  for (int j = 0; j < 10; ++j) s += expf(tv[j] - mx);
  float lse = mx + logf(s);
#pragma unroll
  for (int j = 0; j < 10; ++j) out[(size_t)r * 10 + j] = tv[j] - lse;
}

extern "C" void kernel_launch(void* const* d_in, const int* in_sizes, int n_in,
                              void* d_out, int out_size, void* d_ws, size_t ws_size,
                              hipStream_t stream) {
  const float* x   = (const float*)d_in[0];
  const float* w0f = (const float*)d_in[1];
  const float* w1f = (const float*)d_in[3];
  const float* w2f = (const float*)d_in[5];
  const float* w3f = (const float*)d_in[7];  const float* b3f = (const float*)d_in[8];
  const float* w4f = (const float*)d_in[9];  const float* b4f = (const float*)d_in[10];
  const float* w5f = (const float*)d_in[11];
  const float* g0 = (const float*)d_in[13]; const float* be0 = (const float*)d_in[14];
  const float* g1 = (const float*)d_in[15]; const float* be1 = (const float*)d_in[16];
  const float* g2 = (const float*)d_in[17]; const float* be2 = (const float*)d_in[18];
  const float* g3 = (const float*)d_in[19]; const float* be3 = (const float*)d_in[20];

  const int M = in_sizes[0] / 3072;   // 16384
  char* w = (char*)d_ws;
  short* Abuf          = (short*)w;                          // 134217728
  unsigned char* X0p   = (unsigned char*)(w + 134217728);    // 25165824 (packed fp4)
  unsigned char* Xbp   = (unsigned char*)(w + 184549376);    // 33554432 (packed fp4)
  signed char* X3      = (signed char*)(w + 251658240);      // 4194304 (i8)
  unsigned char* Ws0p  = (unsigned char*)(w + 255852544);    // 6291456
  unsigned char* Ws1p  = (unsigned char*)(w + 268435456);    // 8388608
  unsigned char* Ws2p  = (unsigned char*)(w + 285212672);    // 524288
  signed char* Ws3 = (signed char*)(w + 286261248);          // 4096 (i8)
  signed char* Ws4 = (signed char*)(w + 286265344);          // 256
  signed char* Ws5 = (signed char*)(w + 286265600);          // 160
  int* A5          = (int*)(w + 286265856);                  // 655360
  ull* S0          = (ull*)(w + 286921216);
  ull* S1          = (ull*)(w + 286986752);
  ull* S2          = (ull*)(w + 287052288);
  ull* S5          = (ull*)(w + 287056384);
  float* P0m = (float*)(w + 287056640); float* P0s = (float*)(w + 287073024);
  float* P1m = (float*)(w + 287089408); float* P1s = (float*)(w + 287105792);
  float* P2m = (float*)(w + 287122176); float* P2s = (float*)(w + 287123200);
  float* P5m = (float*)(w + 287124224); float* P5s = (float*)(w + 287124288);

  hipMemsetAsync(w + 286921216, 0, 135424, stream);

  auto binp = [&](const float* src, unsigned char* dst, int n) {
    int n8 = n / 8;
    int grid = (n8 + 255) / 256; if (grid > 8192) grid = 8192;
    k_binp<<<grid, 256, 0, stream>>>((const float4*)src, (uint*)dst, n8);
  };
  binp(x,   X0p,  M * 3072);
  binp(w0f, Ws0p, 4096 * 3072);
  binp(w1f, Ws1p, 4096 * 4096);
  binp(w2f, Ws2p, 256 * 4096);
  k_bin<<<1, 64, 0, stream>>>((const float4*)w3f, (char4*)Ws3, 16 * 256 / 4);
  k_bin<<<1, 64, 0, stream>>>((const float4*)w4f, (char4*)Ws4, 16 * 16 / 4);
  k_bin<<<1, 40, 0, stream>>>((const float4*)w5f, (char4*)Ws5, 10 * 16 / 4);

  // Layer 0: [M,3072] x [4096,3072]^T  (stats fused into GEMM epilogue)
  k_bgemm<<<dim3(4096 / BN, M / BM), 256, 0, stream>>>(X0p, Ws0p, Abuf, S0, M, 4096, 3072);
  k_finalize<<<16, 256, 0, stream>>>(S0, g0, M, 4096, P0m, P0s);
  k_signbn_pack<<<8192, 256, 0, stream>>>(Abuf, P0m, P0s, be0, (uint*)Xbp, M * 4096 / 8, 4095);

  // Layer 1: [M,4096] x [4096,4096]^T
  k_bgemm<<<dim3(4096 / BN, M / BM), 256, 0, stream>>>(Xbp, Ws1p, Abuf, S1, M, 4096, 4096);
  k_finalize<<<16, 256, 0, stream>>>(S1, g1, M, 4096, P1m, P1s);
  k_signbn_pack<<<8192, 256, 0, stream>>>(Abuf, P1m, P1s, be1, (uint*)Xbp, M * 4096 / 8, 4095);

  // Layer 2: [M,4096] x [256,4096]^T  (output X3 stays i8 for the tail)
  k_bgemm<<<dim3(256 / BN, M / BM), 256, 0, stream>>>(Xbp, Ws2p, Abuf, S2, M, 256, 4096);
  k_finalize<<<1, 256, 0, stream>>>(S2, g2, M, 256, P2m, P2s);
  k_signbn<<<4096, 256, 0, stream>>>((const short4*)Abuf, P2m, P2s, be2, (char4*)X3, M * 256 / 4, 255);

  // Layers 3-5 fused + L5 stats
  k_tail<<<M / 16, 256, 0, stream>>>(X3, Ws3, Ws4, Ws5, b3f, b4f, A5, S5, M);
  k_finalize<<<1, 32, 0, stream>>>(S5, g3, M, 10, P5m, P5s);
  k_lsm<<<(M + 255) / 256, 256, 0, stream>>>(A5, P5m, P5s, be3, (float*)d_out, M);

  (void)n_in; (void)out_size; (void)ws_size;
}